// Round 9
// baseline (336.692 us; speedup 1.0000x reference)
//
#include <hip/hip_runtime.h>
#include <hip/hip_bf16.h>

#define NN 384
#define EE 12288
#define DD 1280
#define HH 128
#define DISROWS (NN*NN)

typedef short bf16x8 __attribute__((ext_vector_type(8)));
typedef short bf16x4 __attribute__((ext_vector_type(4)));
typedef float f32x4  __attribute__((ext_vector_type(4)));

__device__ __forceinline__ unsigned short f2bf(float x){
  unsigned u = __builtin_bit_cast(unsigned, x);
  u += 0x7fffu + ((u >> 16) & 1u);
  return (unsigned short)(u >> 16);
}
__device__ __forceinline__ float bf2f(unsigned short h){
  unsigned u = ((unsigned)h) << 16;
  return __builtin_bit_cast(float, u);
}
__device__ __forceinline__ short f2bf_fast(float x){
  return (short)__bfloat16_as_ushort(__float2bfloat16(x));
}
__device__ __forceinline__ void glds16(const short* g, short* l){
  __builtin_amdgcn_global_load_lds((const __attribute__((address_space(1))) void*)g,
                                   (__attribute__((address_space(3))) void*)l, 16, 0, 0);
}

// ---- grid barrier (device-scope atomics; count self-resets; gen monotone) ----
__device__ __forceinline__ void gridbar(int* ibar){
  __syncthreads();
  if (threadIdx.x == 0){
    __threadfence();
    int g = atomicAdd(&ibar[1], 0);
    int v = atomicAdd(&ibar[0], 1);
    if (v == 255){
      atomicExch(&ibar[0], 0);
      atomicAdd(&ibar[1], 1);
    } else {
      int iters = 0;
      while (atomicAdd(&ibar[1], 0) == g && iters < (1<<20)){
        ++iters;
        __builtin_amdgcn_s_sleep(8);
      }
    }
    __threadfence();
  }
  __syncthreads();
}

// transpose W[R][C] tile -> Thi/Tlo[C][R] bf16 hi(+lo). 512 threads.
__device__ __forceinline__ void tsplit512(const float* __restrict__ W,
                                          short* __restrict__ Thi, short* __restrict__ Tlo,
                                          int R, int C, int bx, int by, int t, float* tile){
  int rb = by*64, cb = bx*64;
  int r = t >> 3, cs = (t & 7)*8;
  const float* sp = W + (long)(rb + r)*C + cb + cs;
  f32x4 v0 = *(const f32x4*)sp;
  f32x4 v1 = *(const f32x4*)(sp + 4);
  tile[r*65 + cs+0] = v0[0]; tile[r*65 + cs+1] = v0[1];
  tile[r*65 + cs+2] = v0[2]; tile[r*65 + cs+3] = v0[3];
  tile[r*65 + cs+4] = v1[0]; tile[r*65 + cs+5] = v1[1];
  tile[r*65 + cs+6] = v1[2]; tile[r*65 + cs+7] = v1[3];
  __syncthreads();
  int cp = t >> 3, rs = (t & 7)*8;
  bf16x8 vh, vl;
  #pragma unroll
  for (int i = 0; i < 8; ++i){
    float f = tile[(rs+i)*65 + cp];
    unsigned short h = f2bf(f);
    vh[i] = (short)h; vl[i] = (short)f2bf(f - bf2f(h));
  }
  long ob = (long)(cb + cp)*R + rb + rs;
  *(bf16x8*)&Thi[ob] = vh;
  if (Tlo) *(bf16x8*)&Tlo[ob] = vl;
}

// ---- agg: Y[v] = X[v] + sum_e w_e X[src[e]]; 768 tasks (node x d-half) ----
__device__ void agg_stage(const float* __restrict__ X, float* __restrict__ Y,
                          const float* __restrict__ ew, const int* __restrict__ src_,
                          const int* __restrict__ offs, const int* __restrict__ sorted,
                          int b, int t, char* sm){
  int*   s_off = (int*)sm;
  float* s_w   = (float*)(sm + 2048);
  for (int u = b; u < 768; u += 256){
    int v = u >> 1;
    int dh = (u & 1)*640;
    int d0 = dh + t;
    int d1 = dh + 512 + t;       // valid for t<128
    float a0 = X[(long)v*DD + d0];
    float a1 = (t < 128) ? X[(long)v*DD + d1] : 0.f;
    const int eb = offs[v], ee = offs[v+1];
    for (int c0 = eb; c0 < ee; c0 += 512){
      int n = ee - c0; if (n > 512) n = 512;
      __syncthreads();
      if (t < n){
        int eid = sorted[c0 + t];
        s_off[t] = src_[eid]*DD;
        s_w[t]   = ew[eid];
      }
      __syncthreads();
      int k = 0;
      for (; k + 4 <= n; k += 4){
        a0 += s_w[k]*X[s_off[k]+d0];   a0 += s_w[k+1]*X[s_off[k+1]+d0];
        a0 += s_w[k+2]*X[s_off[k+2]+d0]; a0 += s_w[k+3]*X[s_off[k+3]+d0];
        if (t < 128){
          a1 += s_w[k]*X[s_off[k]+d1];   a1 += s_w[k+1]*X[s_off[k+1]+d1];
          a1 += s_w[k+2]*X[s_off[k+2]+d1]; a1 += s_w[k+3]*X[s_off[k+3]+d1];
        }
      }
      for (; k < n; ++k){
        a0 += s_w[k]*X[s_off[k]+d0];
        if (t < 128) a1 += s_w[k]*X[s_off[k]+d1];
      }
    }
    Y[(long)v*DD + d0] = a0;
    if (t < 128) Y[(long)v*DD + d1] = a1;
    __syncthreads();
  }
}

// ---- gemm: 128m x 64n tiles, split-K=4 (240 tasks), split-bf16 3-product ----
__device__ void gemm_stage(const float* __restrict__ Y, const short* __restrict__ Whi,
                           const short* __restrict__ Wlo, float* __restrict__ P,
                           int b, int t, char* sm){
  if (b < 240){
    short* Ahi = (short*)sm;          // 128*40
    short* Alo = Ahi + 5120;
    short* Bhi = Alo + 5120;          // 64*40
    short* Blo = Bhi + 2560;
    const int z = b / 60, rest = b % 60;
    const int m0 = (rest % 3)*128, n0 = (rest / 3)*64;
    const int kbase = z*320;
    const int w = t >> 6, lane = t & 63, l15 = lane & 15, l4 = lane >> 4;
    f32x4 acc[4];
    #pragma unroll
    for (int n = 0; n < 4; ++n) acc[n] = (f32x4){0.f,0.f,0.f,0.f};
    const int arow = t >> 2, aq = t & 3;
    const float* ap = Y + (long)(m0 + arow)*DD + aq*8;
    for (int kk = 0; kk < 10; ++kk){
      const int d0 = kbase + kk*32;
      __syncthreads();
      {
        f32x4 v0 = *(const f32x4*)(ap + d0);
        f32x4 v1 = *(const f32x4*)(ap + d0 + 4);
        bf16x8 vh, vl;
        #pragma unroll
        for (int q = 0; q < 4; ++q){
          unsigned short h0 = f2bf(v0[q]);
          vh[q]   = (short)h0; vl[q]   = (short)f2bf(v0[q] - bf2f(h0));
          unsigned short h1 = f2bf(v1[q]);
          vh[4+q] = (short)h1; vl[4+q] = (short)f2bf(v1[q] - bf2f(h1));
        }
        *(bf16x8*)&Ahi[arow*40 + aq*8] = vh;
        *(bf16x8*)&Alo[arow*40 + aq*8] = vl;
      }
      if (t < 256){
        const short* bph = Whi + (long)(n0 + (t>>2))*DD + (t&3)*8 + d0;
        const short* bpl = Wlo + (long)(n0 + (t>>2))*DD + (t&3)*8 + d0;
        *(bf16x8*)&Bhi[(t>>2)*40 + (t&3)*8] = *(const bf16x8*)bph;
        *(bf16x8*)&Blo[(t>>2)*40 + (t&3)*8] = *(const bf16x8*)bpl;
      }
      __syncthreads();
      bf16x8 ah = *(const bf16x8*)&Ahi[(w*16 + l15)*40 + l4*8];
      bf16x8 al = *(const bf16x8*)&Alo[(w*16 + l15)*40 + l4*8];
      #pragma unroll
      for (int n = 0; n < 4; ++n){
        bf16x8 bh = *(const bf16x8*)&Bhi[(n*16 + l15)*40 + l4*8];
        bf16x8 bl = *(const bf16x8*)&Blo[(n*16 + l15)*40 + l4*8];
        acc[n] = __builtin_amdgcn_mfma_f32_16x16x32_bf16(ah, bh, acc[n], 0,0,0);
        acc[n] = __builtin_amdgcn_mfma_f32_16x16x32_bf16(ah, bl, acc[n], 0,0,0);
        acc[n] = __builtin_amdgcn_mfma_f32_16x16x32_bf16(al, bh, acc[n], 0,0,0);
      }
    }
    float* Pz = P + (long)z*NN*DD;
    #pragma unroll
    for (int n = 0; n < 4; ++n){
      int gc = n0 + n*16 + l15;
      #pragma unroll
      for (int r = 0; r < 4; ++r)
        Pz[(long)(m0 + w*16 + l4*4 + r)*DD + gc] = acc[n][r];
    }
  }
}

__device__ void red_stage(const float* __restrict__ P, const float* __restrict__ bias,
                          const float* __restrict__ resid, float* __restrict__ Out,
                          int b, int t){
  if (t < 480){
    const int i = b*480 + t;
    const int col = (i*4) % DD;
    const f32x4* P4 = (const f32x4*)P;
    f32x4 s = P4[i];
    s += P4[i + 122880];
    s += P4[i + 2*122880];
    s += P4[i + 3*122880];
    s += *(const f32x4*)(bias + col);
    if (resid) s += ((const f32x4*)resid)[i];
    ((f32x4*)Out)[i] = s;
  }
}

// ---------------- fused chain: feat|CSR|Wprep -> agg0 -> gemm0 -> red0 -> agg1 -> gemm1 -> red1 ----------------
__global__ __launch_bounds__(512, 4)
void k_chain(const float* __restrict__ lm, const float* __restrict__ nf,
             const int* __restrict__ dst_, const float* __restrict__ ef,
             const int* __restrict__ src_,
             const float* __restrict__ Wg0, const float* __restrict__ Wg1,
             const float* __restrict__ Wd1, const float* __restrict__ Wd2,
             const float* __restrict__ bg0, const float* __restrict__ bg1,
             int* ibar, int* gcnt, int* offs, int* basep, int* sorted,
             float* ew, float* x0, float* yb, float* hb,
             short* WtAh, short* WtAl, short* WtBh, short* WtBl,
             short* W1t, short* W2t, float* P){
  __shared__ __align__(16) char sm[40960];
  const int b = blockIdx.x, t = threadIdx.x;

  // ---- S0: feat concat + edge weights + degree count + weight transposes ----
  if (t < 480){
    int i = (b*480 + t)*4;
    int n = i / 1280, d = i - n*1280;
    f32x4 v;
    if (d < 1024) v = *(const f32x4*)&lm[(n+1)*1024 + d];
    else          v = *(const f32x4*)&nf[n*256 + (d-1024)];
    *(f32x4*)&x0[i] = v;
  }
  if (t < 48){
    int e = b*48 + t;
    float f = ef[e];
    ew[e] = 1.0f/(f*f + 1e-6f);
    atomicAdd(&gcnt[dst_[e]], 1);
  }
  {
    float* tile = (float*)sm;
    for (int u = b; u < 841; u += 256){
      __syncthreads();
      if (u < 400)       tsplit512(Wg0, WtAh, WtAl, DD, DD, u % 20, u / 20, t, tile);
      else if (u < 800){ int g = u - 400; tsplit512(Wg1, WtBh, WtBl, DD, DD, g % 20, g / 20, t, tile); }
      else if (u < 840){ int g = u - 800; tsplit512(Wd1, W1t, nullptr, DD, HH, g & 1, g >> 1, t, tile); }
      else {
        for (int i = t; i < 32*HH; i += 512){
          int c = i >> 7, h = i & 127;
          float v = (c < 30) ? Wd2[h*30 + c] : 0.f;
          W2t[i] = (short)f2bf(v);
        }
      }
    }
  }
  gridbar(ibar);
  // ---- S1: scan (block 0) ----
  if (b == 0){
    int* s = (int*)sm;
    int c = (t < NN) ? gcnt[t] : 0;
    s[t] = c;
    __syncthreads();
    for (int off = 1; off < 512; off <<= 1){
      int v = (t >= off) ? s[t-off] : 0;
      __syncthreads();
      s[t] += v;
      __syncthreads();
    }
    if (t < NN){
      int excl = s[t] - c;
      offs[t] = excl;
      basep[t] = excl;
    }
    if (t == 0) offs[NN] = EE;
  }
  gridbar(ibar);
  // ---- S2: place ----
  if (t < 48){
    int e = b*48 + t;
    int p = atomicAdd(&basep[dst_[e]], 1);
    sorted[p] = e;
  }
  gridbar(ibar);
  // ---- S3..S8 ----
  agg_stage(x0, yb, ew, src_, offs, sorted, b, t, sm);
  gridbar(ibar);
  gemm_stage(yb, WtAh, WtAl, P, b, t, sm);
  gridbar(ibar);
  red_stage(P, bg0, nullptr, hb, b, t);
  gridbar(ibar);
  agg_stage(hb, yb, ew, src_, offs, sorted, b, t, sm);
  gridbar(ibar);
  gemm_stage(yb, WtBh, WtBl, P, b, t, sm);
  gridbar(ibar);
  red_stage(P, bg1, x0, hb, b, t);
}

// ---------------- fused dis MLP v6 (R6 measured-best) + mask head ----------------
__launch_bounds__(256, 3)
__global__ void k_dis(const float* __restrict__ X, const short* __restrict__ W1t,
                      const float* __restrict__ bd1, const short* __restrict__ W2t,
                      const float* __restrict__ bd2, float* __restrict__ out,
                      const int* __restrict__ midx,
                      const float* __restrict__ Wm1, const float* __restrict__ bm1,
                      const float* __restrict__ Wm2, const float* __restrict__ bm2){
  __shared__ __align__(16) short smem[25088];   // 50176 B
  const int b = blockIdx.x;
  const int t = threadIdx.x;

  if (b >= 600){
    // ---- mask head ----
    float* tl = (float*)smem;
    int m = b - 600;
    if (t < HH){
      const float* x = X + (long)midx[m]*DD;
      float a0 = 0.f, a1 = 0.f, a2 = 0.f, a3 = 0.f;
      for (int d = 0; d < DD; d += 4){
        a0 += x[d]   * Wm1[(d)*HH + t];
        a1 += x[d+1] * Wm1[(d+1)*HH + t];
        a2 += x[d+2] * Wm1[(d+2)*HH + t];
        a3 += x[d+3] * Wm1[(d+3)*HH + t];
      }
      float v = a0 + a1 + a2 + a3 + bm1[t];
      tl[t] = v > 0.f ? v : 0.f;
    }
    __syncthreads();
    if (t < 2){
      float s = bm2[t];
      for (int h = 0; h < HH; ++h) s += tl[h]*Wm2[h*2 + t];
      out[(long)DISROWS*30 + m*2 + t] = tanhf(s);
    }
    return;
  }

  // triangular unrank: ib pairs (2k,2k+1) each have 24-k tiles
  int k = 0, rem = b;
  while (rem >= 2*(24 - k)){ rem -= 2*(24 - k); ++k; }
  int ib = 2*k;
  if (rem >= 24 - k){ ++ib; rem -= 24 - k; }
  const int jb = k + rem;
  const int i0 = ib*8, j0 = jb*16;

  const int w = t >> 6, lane = t & 63;
  const int l15 = lane & 15, l4 = lane >> 4;

  short* WA = smem;                       // [2][128][64] shorts (32768 B)
  float* XF = (float*)(smem + 16384);     // [2][24][68] f32 (13056 B)
  short* TL = smem;                       // alias: [128][136] shorts (34816 B)
  float* OT = (float*)(smem + 17408);     // alias: [128][30] f32 (15360 B)

  f32x4 acc[2][8];
  #pragma unroll
  for (int m = 0; m < 2; ++m)
    #pragma unroll
    for (int n = 0; n < 8; ++n) acc[m][n] = (f32x4){0.f,0.f,0.f,0.f};

  // W staging: wave w, inst i covers h rows [w*32+i*8, +8); lane -> h += lane>>3, slot lane&7
  const short* wsrc[4];
  #pragma unroll
  for (int i = 0; i < 4; ++i){
    int hb = w*32 + i*8 + (lane >> 3);
    wsrc[i] = W1t + (long)hb*DD + (((lane & 7) ^ (hb & 7))*8);
  }
  // X staging: 1536 f32/macro; thread t, g: idx=g*256+t; row=idx>>6 (0..23), col=idx&63
  const float* xsrc[6];
  int xli[6];
  #pragma unroll
  for (int g = 0; g < 6; ++g){
    int idx = g*256 + t;
    int rowl = idx >> 6, col = idx & 63;
    int grow = (rowl < 8) ? (i0 + rowl) : (j0 + rowl - 8);
    xsrc[g] = X + (long)grow*DD + col;
    xli[g] = rowl*68 + col;
  }

  // prologue: macro 0
  float xr[6];
  #pragma unroll
  for (int i = 0; i < 4; ++i)
    glds16(wsrc[i], WA + (w*32 + i*8)*64);
  #pragma unroll
  for (int g = 0; g < 6; ++g) xr[g] = xsrc[g][0];
  #pragma unroll
  for (int g = 0; g < 6; ++g) XF[xli[g]] = xr[g];
  __syncthreads();

  for (int mk = 0; mk < 20; ++mk){
    const int cb = mk & 1;
    short* WAc = WA + cb*8192;
    float* XFc = XF + cb*1632;
    short* WAn = WA + (cb^1)*8192;
    float* XFn = XF + (cb^1)*1632;
    if (mk < 19){
      #pragma unroll
      for (int i = 0; i < 4; ++i)
        glds16(wsrc[i] + (mk+1)*64, WAn + (w*32 + i*8)*64);
      #pragma unroll
      for (int g = 0; g < 6; ++g) xr[g] = xsrc[g][(mk+1)*64];
    }
    #pragma unroll
    for (int ks = 0; ks < 2; ++ks){
      f32x4 xj0 = *(const f32x4*)&XFc[(8 + l15)*68 + ks*32 + l4*8];
      f32x4 xj1 = *(const f32x4*)&XFc[(8 + l15)*68 + ks*32 + l4*8 + 4];
      bf16x8 a[2];
      #pragma unroll
      for (int m = 0; m < 2; ++m){
        const float* xip = &XFc[(2*w + m)*68 + ks*32 + l4*8];
        f32x4 xi0 = *(const f32x4*)xip;
        f32x4 xi1 = *(const f32x4*)(xip + 4);
        bf16x8 av;
        #pragma unroll
        for (int q = 0; q < 4; ++q){ float dl = xj0[q]-xi0[q]; av[q]   = f2bf_fast(dl*dl); }
        #pragma unroll
        for (int q = 0; q < 4; ++q){ float dl = xj1[q]-xi1[q]; av[4+q] = f2bf_fast(dl*dl); }
        a[m] = av;
      }
      #pragma unroll
      for (int n = 0; n < 8; ++n){
        bf16x8 wf = *(const bf16x8*)&WAc[(n*16 + l15)*64 + (((ks*4 + l4) ^ (l15 & 7))*8)];
        acc[0][n] = __builtin_amdgcn_mfma_f32_16x16x32_bf16(wf, a[0], acc[0][n], 0,0,0);
        acc[1][n] = __builtin_amdgcn_mfma_f32_16x16x32_bf16(wf, a[1], acc[1][n], 0,0,0);
      }
    }
    if (mk < 19){
      #pragma unroll
      for (int g = 0; g < 6; ++g) XFn[xli[g]] = xr[g];
    }
    __syncthreads();
  }

  // ---- TL[pair][h] write (b64 packed, 4 consecutive h) ----
  f32x4 bd1v[8];
  #pragma unroll
  for (int n = 0; n < 8; ++n) bd1v[n] = *(const f32x4*)(bd1 + n*16 + l4*4);
  #pragma unroll
  for (int m = 0; m < 2; ++m){
    int pair = (2*w + m)*16 + l15;
    #pragma unroll
    for (int n = 0; n < 8; ++n){
      bf16x4 pv;
      #pragma unroll
      for (int r = 0; r < 4; ++r){
        float v = acc[m][n][r] + bd1v[n][r];
        v = v > 0.f ? v : 0.f;
        pv[r] = f2bf_fast(v);
      }
      *(bf16x4*)&TL[pair*136 + n*16 + l4*4] = pv;
    }
  }
  __syncthreads();

  // ---- layer 2: wave w owns pairs [w*32, +32) ----
  f32x4 acc2[2][2];
  #pragma unroll
  for (int m2 = 0; m2 < 2; ++m2)
    #pragma unroll
    for (int nn = 0; nn < 2; ++nn) acc2[m2][nn] = (f32x4){0.f,0.f,0.f,0.f};
  #pragma unroll
  for (int hs = 0; hs < 4; ++hs){
    bf16x8 b2[2];
    #pragma unroll
    for (int nn = 0; nn < 2; ++nn)
      b2[nn] = *(const bf16x8*)&W2t[(nn*16 + l15)*HH + hs*32 + l4*8];
    #pragma unroll
    for (int m2 = 0; m2 < 2; ++m2){
      bf16x8 a2 = *(const bf16x8*)&TL[(w*32 + m2*16 + l15)*136 + hs*32 + l4*8];
      #pragma unroll
      for (int nn = 0; nn < 2; ++nn)
        acc2[m2][nn] = __builtin_amdgcn_mfma_f32_16x16x32_bf16(a2, b2[nn], acc2[m2][nn], 0,0,0);
    }
  }
  // OT[pair][30] f32
  #pragma unroll
  for (int m2 = 0; m2 < 2; ++m2){
    #pragma unroll
    for (int nn = 0; nn < 2; ++nn){
      int cc = nn*16 + l15;
      if (cc < 30){
        float b2v = bd2[cc];
        #pragma unroll
        for (int r = 0; r < 4; ++r)
          OT[(w*32 + m2*16 + l4*4 + r)*30 + cc] = acc2[m2][nn][r] + b2v;
      }
    }
  }
  __syncthreads();

  // ---- coalesced global writes from OT ----
  {
    // normal tile: 8 rows (gi), each 480 f32 contiguous
    int i = t >> 5;
    int ca = (t & 31)*15;
    long nbase = ((long)(i0 + i)*NN + j0)*30 + ca;
    const float* nsrc = OT + i*480 + ca;
    #pragma unroll
    for (int q = 0; q < 15; ++q) out[nbase + q] = nsrc[q];
    // mirror tile: 16 rows (gj), each 240 f32 contiguous
    int j = t >> 4;
    int s = t & 15;
    int ii = s >> 1;
    int c0 = (s & 1)*15;
    long mbase = ((long)(j0 + j)*NN + i0 + ii)*30 + c0;
    const float* msrc = OT + ii*480 + j*30 + c0;
    #pragma unroll
    for (int q = 0; q < 15; ++q) out[mbase + q] = msrc[q];
  }
}

// ---------------- launch ----------------
extern "C" void kernel_launch(void* const* d_in, const int* in_sizes, int n_in,
                              void* d_out, int out_size, void* d_ws, size_t ws_size,
                              hipStream_t stream){
  const float* lm   = (const float*)d_in[0];
  const float* nf   = (const float*)d_in[1];
  const float* ef   = (const float*)d_in[2];
  const int*   src  = (const int*)d_in[3];
  const int*   dst  = (const int*)d_in[4];
  const int*   midx = (const int*)d_in[5];
  const float* Wg0  = (const float*)d_in[6];
  const float* bg0  = (const float*)d_in[7];
  const float* Wg1  = (const float*)d_in[8];
  const float* bg1  = (const float*)d_in[9];
  const float* Wd1  = (const float*)d_in[10];
  const float* bd1  = (const float*)d_in[11];
  const float* Wd2  = (const float*)d_in[12];
  const float* bd2  = (const float*)d_in[13];
  const float* Wm1  = (const float*)d_in[14];
  const float* bm1  = (const float*)d_in[15];
  const float* Wm2  = (const float*)d_in[16];
  const float* bm2  = (const float*)d_in[17];
  float* dis = (float*)d_out;

  char* ws = (char*)d_ws;
  size_t off = 0;
  auto alloc = [&](size_t bytes)->void*{
    void* p = ws + off; off += (bytes + 255) & ~(size_t)255; return p;
  };
  int*   ibar   = (int*)alloc(4096);            // [0] count, [1] gen, [16..400) gcnt
  int*   gcnt   = ibar + 16;
  int*   offs   = (int*)alloc((NN+1)*4);
  int*   basep  = (int*)alloc(NN*4);
  int*   sorted = (int*)alloc(EE*4);
  float* ew     = (float*)alloc((size_t)EE*4);
  float* x0     = (float*)alloc((size_t)NN*DD*4);
  float* yb     = (float*)alloc((size_t)NN*DD*4);
  float* hb     = (float*)alloc((size_t)NN*DD*4);
  short* WtAh   = (short*)alloc((size_t)DD*DD*2);
  short* WtAl   = (short*)alloc((size_t)DD*DD*2);
  short* WtBh   = (short*)alloc((size_t)DD*DD*2);
  short* WtBl   = (short*)alloc((size_t)DD*DD*2);
  short* W1t    = (short*)alloc((size_t)HH*DD*2);
  short* W2t    = (short*)alloc((size_t)32*HH*2);
  float* P      = (float*)alloc((size_t)4*NN*DD*4);

  hipMemsetAsync(ibar, 0, 4096, stream);
  k_chain<<<256, 512, 0, stream>>>(lm, nf, dst, ef, src,
                                   Wg0, Wg1, Wd1, Wd2, bg0, bg1,
                                   ibar, gcnt, offs, basep, sorted,
                                   ew, x0, yb, hb,
                                   WtAh, WtAl, WtBh, WtBl, W1t, W2t, P);
  k_dis<<<664, 256, 0, stream>>>(hb, W1t, bd1, W2t, bd2, dis,
                                 midx, Wm1, bm1, Wm2, bm2);
}

// Round 10
// 147.018 us; speedup vs baseline: 2.2901x; 2.2901x over previous
//
#include <hip/hip_runtime.h>
#include <hip/hip_bf16.h>

#define NN 384
#define EE 12288
#define DD 1280
#define HH 128
#define DISROWS (NN*NN)

typedef short bf16x8 __attribute__((ext_vector_type(8)));
typedef short bf16x4 __attribute__((ext_vector_type(4)));
typedef float f32x4  __attribute__((ext_vector_type(4)));

__device__ __forceinline__ unsigned short f2bf(float x){
  unsigned u = __builtin_bit_cast(unsigned, x);
  u += 0x7fffu + ((u >> 16) & 1u);
  return (unsigned short)(u >> 16);
}
__device__ __forceinline__ float bf2f(unsigned short h){
  unsigned u = ((unsigned)h) << 16;
  return __builtin_bit_cast(float, u);
}
__device__ __forceinline__ short f2bf_fast(float x){
  return (short)__bfloat16_as_ushort(__float2bfloat16(x));
}
__device__ __forceinline__ void glds16(const short* g, short* l){
  __builtin_amdgcn_global_load_lds((const __attribute__((address_space(1))) void*)g,
                                   (__attribute__((address_space(3))) void*)l, 16, 0, 0);
}

// transpose W[R][C] -> Thi/Tlo[C][R] as bf16 hi (+ optional lo residual). 256 threads.
__device__ __forceinline__ void tsplit_body(const float* __restrict__ W,
                                            short* __restrict__ Thi, short* __restrict__ Tlo,
                                            int R, int C, int bx, int by, int t,
                                            float* tile /* [64][65] shared */){
  int rb = by*64, cb = bx*64;
  int r  = t >> 2;
  int cs = (t & 3) * 16;
  const float* sp = W + (long)(rb + r)*C + cb + cs;
  #pragma unroll
  for (int i = 0; i < 16; i += 4){
    f32x4 v = *(const f32x4*)(sp + i);
    tile[r*65 + cs+i+0] = v[0]; tile[r*65 + cs+i+1] = v[1];
    tile[r*65 + cs+i+2] = v[2]; tile[r*65 + cs+i+3] = v[3];
  }
  __syncthreads();
  int cp = t >> 2;
  int rs = (t & 3) * 16;
  bf16x8 vh0, vh1, vl0, vl1;
  #pragma unroll
  for (int i = 0; i < 8; ++i){
    float f = tile[(rs+i)*65 + cp];
    unsigned short h = f2bf(f);
    vh0[i] = (short)h; vl0[i] = (short)f2bf(f - bf2f(h));
  }
  #pragma unroll
  for (int i = 0; i < 8; ++i){
    float f = tile[(rs+8+i)*65 + cp];
    unsigned short h = f2bf(f);
    vh1[i] = (short)h; vl1[i] = (short)f2bf(f - bf2f(h));
  }
  long ob = (long)(cb + cp)*R + rb + rs;
  *(bf16x8*)&Thi[ob]   = vh0;
  *(bf16x8*)&Thi[ob+8] = vh1;
  if (Tlo){
    *(bf16x8*)&Tlo[ob]   = vl0;
    *(bf16x8*)&Tlo[ob+8] = vl1;
  }
}

// ---------------- mega-prep (512 thr): feat | graph CSR | Wd prep | tsplit(Wg0) ----------------
// blocks: [0,960) feat; [960] graph; [961,1002) dw; [1002,1402) tsplit Wg0
__global__ void k_prep(const float* __restrict__ lm, const float* __restrict__ nf,
                       float* __restrict__ x0,
                       const int* __restrict__ dst, const float* __restrict__ ef,
                       int* __restrict__ offs, int* __restrict__ sorted,
                       float* __restrict__ ew,
                       const float* __restrict__ Wd1, short* __restrict__ W1t,
                       const float* __restrict__ Wd2, short* __restrict__ W2t,
                       const float* __restrict__ Wg0, short* __restrict__ WtAh,
                       short* __restrict__ WtAl){
  __shared__ __align__(16) float sh[64*65];
  const int b = blockIdx.x;
  const int t = threadIdx.x;  // 512
  if (b < 960){
    int i = b*512 + t;
    int n = i / 1280;
    int d = i - n*1280;
    x0[i] = (d < 1024) ? lm[(n+1)*1024 + d] : nf[n*256 + (d-1024)];
    return;
  }
  if (b == 960){
    int* cnt = (int*)sh;
    int* base = cnt + 512;
    if (t < 512) cnt[t] = 0;
    __syncthreads();
    for (int e = t; e < EE; e += 512){
      atomicAdd(&cnt[dst[e]], 1);
      float f = ef[e];
      ew[e] = 1.0f/(f*f + 1e-6f);
    }
    __syncthreads();
    for (int off = 1; off < 512; off <<= 1){
      int v = (t >= off) ? cnt[t - off] : 0;
      __syncthreads();
      cnt[t] += v;
      __syncthreads();
    }
    if (t < NN){
      int excl = t ? cnt[t-1] : 0;
      offs[t] = excl;
      base[t] = excl;
    }
    if (t == 0) offs[NN] = EE;
    __syncthreads();
    for (int e = t; e < EE; e += 512){
      int p = atomicAdd(&base[dst[e]], 1);
      sorted[p] = e;
    }
    return;
  }
  if (b < 1002){
    int g = b - 961;
    if (g < 40){
      if (t < 256) tsplit_body(Wd1, W1t, nullptr, DD, HH, g & 1, g >> 1, t, sh);
      else { __syncthreads(); }
      return;
    }
    for (int i = t; i < 32*HH; i += 512){
      int c = i >> 7, h = i & 127;
      float v = (c < 30) ? Wd2[h*30 + c] : 0.f;
      W2t[i] = (short)f2bf(v);
    }
    return;
  }
  {
    int g = b - 1002;
    if (t < 256) tsplit_body(Wg0, WtAh, WtAl, DD, DD, g % 20, g / 20, t, sh);
    else { __syncthreads(); }
  }
}

// ---------------- edge aggregation ----------------
__global__ void k_agg(const float* __restrict__ X, const float* __restrict__ ew,
                      const int* __restrict__ src, const int* __restrict__ offs,
                      const int* __restrict__ sorted, float* __restrict__ Y){
  __shared__ int   s_off[160];
  __shared__ float s_w[160];
  const int v = blockIdx.x;
  const int d = blockIdx.y*256 + threadIdx.x;
  const int t = threadIdx.x;
  float acc = X[(long)v*DD + d];
  const int b = offs[v], e = offs[v+1];
  for (int c0 = b; c0 < e; c0 += 160){
    int n = e - c0; if (n > 160) n = 160;
    __syncthreads();
    if (t < n){
      int eid = sorted[c0 + t];
      s_off[t] = src[eid]*DD;
      s_w[t]   = ew[eid];
    }
    __syncthreads();
    int k = 0;
    for (; k + 4 <= n; k += 4){
      acc += s_w[k]  *X[s_off[k]   + d];
      acc += s_w[k+1]*X[s_off[k+1] + d];
      acc += s_w[k+2]*X[s_off[k+2] + d];
      acc += s_w[k+3]*X[s_off[k+3] + d];
    }
    for (; k < n; ++k) acc += s_w[k]*X[s_off[k] + d];
  }
  Y[(long)v*DD + d] = acc;
}

// ---------------- GIN GEMM, split-K=4 ----------------
__launch_bounds__(256, 2)
__global__ void k_gin_gemm(const float* __restrict__ Y, const short* __restrict__ Whi,
                           const short* __restrict__ Wlo, float* __restrict__ P){
  __shared__ __align__(16) short Ahi[128*40], Alo[128*40], Bhi[128*40], Blo[128*40];
  const int m0 = blockIdx.x*128;
  const int n0 = blockIdx.y*128;
  const int kbase = blockIdx.z*320;
  const int t = threadIdx.x, w = t >> 6, lane = t & 63;
  const int l15 = lane & 15, l4 = lane >> 4;
  f32x4 acc[2][8];
  #pragma unroll
  for (int m = 0; m < 2; ++m)
    #pragma unroll
    for (int n = 0; n < 8; ++n) acc[m][n] = (f32x4){0.f,0.f,0.f,0.f};

  const int row = t >> 1, half = t & 1;
  const float* ap  = Y   + (long)(m0+row)*DD + half*16;
  const short* bph = Whi + (long)(n0+row)*DD + half*16;
  const short* bpl = Wlo + (long)(n0+row)*DD + half*16;

  for (int kk = 0; kk < 10; ++kk){
    int d0 = kbase + kk*32;
    __syncthreads();
    #pragma unroll
    for (int g = 0; g < 2; ++g){
      f32x4 v0 = *(const f32x4*)(ap + d0 + g*8);
      f32x4 v1 = *(const f32x4*)(ap + d0 + g*8 + 4);
      bf16x8 vh, vl;
      #pragma unroll
      for (int q = 0; q < 4; ++q){
        unsigned short h0 = f2bf(v0[q]);
        vh[q]   = (short)h0; vl[q]   = (short)f2bf(v0[q] - bf2f(h0));
        unsigned short h1 = f2bf(v1[q]);
        vh[4+q] = (short)h1; vl[4+q] = (short)f2bf(v1[q] - bf2f(h1));
      }
      *(bf16x8*)&Ahi[row*40 + half*16 + g*8] = vh;
      *(bf16x8*)&Alo[row*40 + half*16 + g*8] = vl;
    }
    *(bf16x8*)&Bhi[row*40 + half*16]     = *(const bf16x8*)(bph + d0);
    *(bf16x8*)&Bhi[row*40 + half*16 + 8] = *(const bf16x8*)(bph + d0 + 8);
    *(bf16x8*)&Blo[row*40 + half*16]     = *(const bf16x8*)(bpl + d0);
    *(bf16x8*)&Blo[row*40 + half*16 + 8] = *(const bf16x8*)(bpl + d0 + 8);
    __syncthreads();

    bf16x8 ah[2], al[2];
    #pragma unroll
    for (int m = 0; m < 2; ++m){
      int rr = w*32 + m*16 + l15;
      ah[m] = *(const bf16x8*)&Ahi[rr*40 + l4*8];
      al[m] = *(const bf16x8*)&Alo[rr*40 + l4*8];
    }
    #pragma unroll
    for (int n = 0; n < 8; ++n){
      int rr = n*16 + l15;
      bf16x8 bh = *(const bf16x8*)&Bhi[rr*40 + l4*8];
      bf16x8 bl = *(const bf16x8*)&Blo[rr*40 + l4*8];
      #pragma unroll
      for (int m = 0; m < 2; ++m){
        acc[m][n] = __builtin_amdgcn_mfma_f32_16x16x32_bf16(ah[m], bh, acc[m][n], 0,0,0);
        acc[m][n] = __builtin_amdgcn_mfma_f32_16x16x32_bf16(ah[m], bl, acc[m][n], 0,0,0);
        acc[m][n] = __builtin_amdgcn_mfma_f32_16x16x32_bf16(al[m], bh, acc[m][n], 0,0,0);
      }
    }
  }
  float* Pz = P + (long)blockIdx.z*NN*DD;
  #pragma unroll
  for (int m = 0; m < 2; ++m){
    #pragma unroll
    for (int n = 0; n < 8; ++n){
      int gr0 = m0 + w*32 + m*16 + l4*4;
      int gc  = n0 + n*16 + l15;
      #pragma unroll
      for (int r = 0; r < 4; ++r)
        Pz[(long)(gr0+r)*DD + gc] = acc[m][n][r];
    }
  }
}

// red: blocks [0,480) sum P + bias (+resid) -> Out; blocks [480,880): tsplit(Wg1) -> WtA
__global__ void k_red_t(const float* __restrict__ P, const float* __restrict__ bias,
                        const float* __restrict__ resid, float* __restrict__ Out,
                        const float* __restrict__ Wg1, short* __restrict__ WtAh,
                        short* __restrict__ WtAl){
  __shared__ __align__(16) float sh[64*65];
  const int b = blockIdx.x;
  if (b >= 480){
    if (Wg1){
      int g = b - 480;
      tsplit_body(Wg1, WtAh, WtAl, DD, DD, g % 20, g / 20, threadIdx.x, sh);
    }
    return;
  }
  const int i = b*256 + threadIdx.x;
  const int col = (i*4) % DD;
  const f32x4* P4 = (const f32x4*)P;
  f32x4 s = P4[i];
  s += P4[i + 122880];
  s += P4[i + 2*122880];
  s += P4[i + 3*122880];
  s += *(const f32x4*)(bias + col);
  if (resid) s += ((const f32x4*)resid)[i];
  ((f32x4*)Out)[i] = s;
}

// ---------------- fused dis MLP v10 (R6 staging + 2x2 wave split) + mask head ----------------
// blocks [0,600): tile (ib: 8 i-rows, jb: 16 j-cols), jb_min = ib>>1. 256 thr / 4 waves.
// Wave w = (wi = w&1, wh = w>>1): i-rows wi*4..+4 (m=4), h-tiles wh*4..+4 (n=4).
// Staging identical to R6: 20 macros of K=64; W [2][128][64] via swizzled glds16;
// X [2][24][68] f32 in LDS (8 i-rows + 16 j-rows), reg-prefetched coalesced.
// Per block per K=32: 16 W + 8 xj wave-reads + xi 4-way-broadcast reads
// = ~24 KB / 64 MFMA = 375 B/MFMA (was 640 in R6).
// Epilogue: TL b64-packed bf16x4; layer-2; OT coalesced writes + mirror.
// blocks [600,664): mask head.
__launch_bounds__(256, 3)
__global__ void k_dis(const float* __restrict__ X, const short* __restrict__ W1t,
                      const float* __restrict__ bd1, const short* __restrict__ W2t,
                      const float* __restrict__ bd2, float* __restrict__ out,
                      const int* __restrict__ midx,
                      const float* __restrict__ Wm1, const float* __restrict__ bm1,
                      const float* __restrict__ Wm2, const float* __restrict__ bm2){
  __shared__ __align__(16) short smem[25088];   // 50176 B
  const int b = blockIdx.x;
  const int t = threadIdx.x;

  if (b >= 600){
    // ---- mask head ----
    float* tl = (float*)smem;
    int m = b - 600;
    if (t < HH){
      const float* x = X + (long)midx[m]*DD;
      float a0 = 0.f, a1 = 0.f, a2 = 0.f, a3 = 0.f;
      for (int d = 0; d < DD; d += 4){
        a0 += x[d]   * Wm1[(d)*HH + t];
        a1 += x[d+1] * Wm1[(d+1)*HH + t];
        a2 += x[d+2] * Wm1[(d+2)*HH + t];
        a3 += x[d+3] * Wm1[(d+3)*HH + t];
      }
      float v = a0 + a1 + a2 + a3 + bm1[t];
      tl[t] = v > 0.f ? v : 0.f;
    }
    __syncthreads();
    if (t < 2){
      float s = bm2[t];
      for (int h = 0; h < HH; ++h) s += tl[h]*Wm2[h*2 + t];
      out[(long)DISROWS*30 + m*2 + t] = tanhf(s);
    }
    return;
  }

  // triangular unrank: ib pairs (2k,2k+1) each have 24-k tiles
  int k = 0, rem = b;
  while (rem >= 2*(24 - k)){ rem -= 2*(24 - k); ++k; }
  int ib = 2*k;
  if (rem >= 24 - k){ ++ib; rem -= 24 - k; }
  const int jb = k + rem;
  const int i0 = ib*8, j0 = jb*16;

  const int w = t >> 6, lane = t & 63;
  const int l15 = lane & 15, l4 = lane >> 4;
  const int wi = w & 1, wh = w >> 1;

  short* WA = smem;                       // [2][128][64] shorts (32768 B)
  float* XF = (float*)(smem + 16384);     // [2][24][68] f32 (13056 B)
  short* TL = smem;                       // alias: [128][136] shorts (34816 B)
  float* OT = (float*)(smem + 17408);     // alias: [128][30] f32 (15360 B)

  f32x4 acc[4][4];
  #pragma unroll
  for (int m = 0; m < 4; ++m)
    #pragma unroll
    for (int n = 0; n < 4; ++n) acc[m][n] = (f32x4){0.f,0.f,0.f,0.f};

  // W staging: wave w, inst i covers h rows [w*32+i*8, +8); lane -> h += lane>>3, slot lane&7
  const short* wsrc[4];
  #pragma unroll
  for (int i = 0; i < 4; ++i){
    int hb = w*32 + i*8 + (lane >> 3);
    wsrc[i] = W1t + (long)hb*DD + (((lane & 7) ^ (hb & 7))*8);
  }
  // X staging: 1536 f32/macro; thread t, g: idx=g*256+t; row=idx>>6 (0..23), col=idx&63
  const float* xsrc[6];
  int xli[6];
  #pragma unroll
  for (int g = 0; g < 6; ++g){
    int idx = g*256 + t;
    int rowl = idx >> 6, col = idx & 63;
    int grow = (rowl < 8) ? (i0 + rowl) : (j0 + rowl - 8);
    xsrc[g] = X + (long)grow*DD + col;
    xli[g] = rowl*68 + col;
  }

  // prologue: macro 0
  float xr[6];
  #pragma unroll
  for (int i = 0; i < 4; ++i)
    glds16(wsrc[i], WA + (w*32 + i*8)*64);
  #pragma unroll
  for (int g = 0; g < 6; ++g) xr[g] = xsrc[g][0];
  #pragma unroll
  for (int g = 0; g < 6; ++g) XF[xli[g]] = xr[g];
  __syncthreads();

  for (int mk = 0; mk < 20; ++mk){
    const int cb = mk & 1;
    short* WAc = WA + cb*8192;
    float* XFc = XF + cb*1632;
    short* WAn = WA + (cb^1)*8192;
    float* XFn = XF + (cb^1)*1632;
    if (mk < 19){
      #pragma unroll
      for (int i = 0; i < 4; ++i)
        glds16(wsrc[i] + (mk+1)*64, WAn + (w*32 + i*8)*64);
      #pragma unroll
      for (int g = 0; g < 6; ++g) xr[g] = xsrc[g][(mk+1)*64];
    }
    #pragma unroll
    for (int ks = 0; ks < 2; ++ks){
      // xj fragment (per-lane row j = l15)
      f32x4 xj0 = *(const f32x4*)&XFc[(8 + l15)*68 + ks*32 + l4*8];
      f32x4 xj1 = *(const f32x4*)&XFc[(8 + l15)*68 + ks*32 + l4*8 + 4];
      // A fragments for this wave's 4 i-rows (xi = broadcast reads)
      bf16x8 a[4];
      #pragma unroll
      for (int m = 0; m < 4; ++m){
        const float* xip = &XFc[(wi*4 + m)*68 + ks*32 + l4*8];
        f32x4 xi0 = *(const f32x4*)xip;
        f32x4 xi1 = *(const f32x4*)(xip + 4);
        bf16x8 av;
        #pragma unroll
        for (int q = 0; q < 4; ++q){ float dl = xj0[q]-xi0[q]; av[q]   = f2bf_fast(dl*dl); }
        #pragma unroll
        for (int q = 0; q < 4; ++q){ float dl = xj1[q]-xi1[q]; av[4+q] = f2bf_fast(dl*dl); }
        a[m] = av;
      }
      // W fragments for this wave's 4 h-tiles
      #pragma unroll
      for (int n = 0; n < 4; ++n){
        const int hrow = (wh*4 + n)*16 + l15;
        bf16x8 wf = *(const bf16x8*)&WAc[hrow*64 + (((ks*4 + l4) ^ (l15 & 7))*8)];
        #pragma unroll
        for (int m = 0; m < 4; ++m)
          acc[m][n] = __builtin_amdgcn_mfma_f32_16x16x32_bf16(wf, a[m], acc[m][n], 0,0,0);
      }
    }
    if (mk < 19){
      #pragma unroll
      for (int g = 0; g < 6; ++g) XFn[xli[g]] = xr[g];
    }
    __syncthreads();
  }

  // ---- TL[pair][h] write (b64 packed, 4 consecutive h) ----
  f32x4 bd1v[4];
  #pragma unroll
  for (int n = 0; n < 4; ++n) bd1v[n] = *(const f32x4*)(bd1 + wh*64 + n*16 + l4*4);
  #pragma unroll
  for (int m = 0; m < 4; ++m){
    int pair = (wi*4 + m)*16 + l15;
    #pragma unroll
    for (int n = 0; n < 4; ++n){
      bf16x4 pv;
      #pragma unroll
      for (int r = 0; r < 4; ++r){
        float v = acc[m][n][r] + bd1v[n][r];
        v = v > 0.f ? v : 0.f;
        pv[r] = f2bf_fast(v);
      }
      *(bf16x4*)&TL[pair*136 + wh*64 + n*16 + l4*4] = pv;
    }
  }
  __syncthreads();

  // ---- layer 2: wave w owns pairs [w*32, +32) ----
  f32x4 acc2[2][2];
  #pragma unroll
  for (int m2 = 0; m2 < 2; ++m2)
    #pragma unroll
    for (int nn = 0; nn < 2; ++nn) acc2[m2][nn] = (f32x4){0.f,0.f,0.f,0.f};
  #pragma unroll
  for (int hs = 0; hs < 4; ++hs){
    bf16x8 b2[2];
    #pragma unroll
    for (int nn = 0; nn < 2; ++nn)
      b2[nn] = *(const bf16x8*)&W2t[(nn*16 + l15)*HH + hs*32 + l4*8];
    #pragma unroll
    for (int m2 = 0; m2 < 2; ++m2){
      bf16x8 a2 = *(const bf16x8*)&TL[(w*32 + m2*16 + l15)*136 + hs*32 + l4*8];
      #pragma unroll
      for (int nn = 0; nn < 2; ++nn)
        acc2[m2][nn] = __builtin_amdgcn_mfma_f32_16x16x32_bf16(a2, b2[nn], acc2[m2][nn], 0,0,0);
    }
  }
  // OT[pair][30] f32
  #pragma unroll
  for (int m2 = 0; m2 < 2; ++m2){
    #pragma unroll
    for (int nn = 0; nn < 2; ++nn){
      int cc = nn*16 + l15;
      if (cc < 30){
        float b2v = bd2[cc];
        #pragma unroll
        for (int r = 0; r < 4; ++r)
          OT[(w*32 + m2*16 + l4*4 + r)*30 + cc] = acc2[m2][nn][r] + b2v;
      }
    }
  }
  __syncthreads();

  // ---- coalesced global writes from OT ----
  {
    // normal tile: 8 rows (gi), each 480 f32 contiguous
    int i = t >> 5;
    int ca = (t & 31)*15;
    long nbase = ((long)(i0 + i)*NN + j0)*30 + ca;
    const float* nsrc = OT + i*480 + ca;
    #pragma unroll
    for (int q = 0; q < 15; ++q) out[nbase + q] = nsrc[q];
    // mirror tile: 16 rows (gj), each 240 f32 contiguous
    int j = t >> 4;
    int s = t & 15;
    int ii = s >> 1;
    int c0 = (s & 1)*15;
    long mbase = ((long)(j0 + j)*NN + i0 + ii)*30 + c0;
    const float* msrc = OT + ii*480 + j*30 + c0;
    #pragma unroll
    for (int q = 0; q < 15; ++q) out[mbase + q] = msrc[q];
  }
}

// ---------------- launch ----------------
extern "C" void kernel_launch(void* const* d_in, const int* in_sizes, int n_in,
                              void* d_out, int out_size, void* d_ws, size_t ws_size,
                              hipStream_t stream){
  const float* lm   = (const float*)d_in[0];
  const float* nf   = (const float*)d_in[1];
  const float* ef   = (const float*)d_in[2];
  const int*   src  = (const int*)d_in[3];
  const int*   dst  = (const int*)d_in[4];
  const int*   midx = (const int*)d_in[5];
  const float* Wg0  = (const float*)d_in[6];
  const float* bg0  = (const float*)d_in[7];
  const float* Wg1  = (const float*)d_in[8];
  const float* bg1  = (const float*)d_in[9];
  const float* Wd1  = (const float*)d_in[10];
  const float* bd1  = (const float*)d_in[11];
  const float* Wd2  = (const float*)d_in[12];
  const float* bd2  = (const float*)d_in[13];
  const float* Wm1  = (const float*)d_in[14];
  const float* bm1  = (const float*)d_in[15];
  const float* Wm2  = (const float*)d_in[16];
  const float* bm2  = (const float*)d_in[17];
  float* dis = (float*)d_out;

  char* ws = (char*)d_ws;
  size_t off = 0;
  auto alloc = [&](size_t bytes)->void*{
    void* p = ws + off; off += (bytes + 255) & ~(size_t)255; return p;
  };
  float* x0   = (float*)alloc((size_t)NN*DD*4);
  float* yb   = (float*)alloc((size_t)NN*DD*4);
  float* hb   = (float*)alloc((size_t)NN*DD*4);
  float* ew   = (float*)alloc((size_t)EE*4);
  int*   offs = (int*)alloc((NN+1)*4);
  int*   sorted = (int*)alloc(EE*4);
  short* WtAh = (short*)alloc((size_t)DD*DD*2);
  short* WtAl = (short*)alloc((size_t)DD*DD*2);
  short* W1t  = (short*)alloc((size_t)HH*DD*2);
  short* W2t  = (short*)alloc((size_t)32*HH*2);
  float* P    = (float*)alloc((size_t)4*NN*DD*4);

  k_prep<<<1402,512,0,stream>>>(lm, nf, x0, dst, ef, offs, sorted, ew,
                                Wd1, W1t, Wd2, W2t, Wg0, WtAh, WtAl);

  k_agg<<<dim3(384,5),256,0,stream>>>(x0, ew, src, offs, sorted, yb);
  k_gin_gemm<<<dim3(3,10,4),256,0,stream>>>(yb, WtAh, WtAl, P);
  k_red_t<<<880,256,0,stream>>>(P, bg0, nullptr, hb, Wg1, WtAh, WtAl);

  k_agg<<<dim3(384,5),256,0,stream>>>(hb, ew, src, offs, sorted, yb);
  k_gin_gemm<<<dim3(3,10,4),256,0,stream>>>(yb, WtAh, WtAl, P);
  k_red_t<<<480,256,0,stream>>>(P, bg1, x0, hb, nullptr, nullptr, nullptr);

  k_dis<<<664,256,0,stream>>>(hb, W1t, bd1, W2t, bd2, dis,
                              midx, Wm1, bm1, Wm2, bm2);
}

// Round 11
// 121.521 us; speedup vs baseline: 2.7706x; 1.2098x over previous
//
#include <hip/hip_runtime.h>
#include <hip/hip_bf16.h>

#define NN 384
#define EE 12288
#define DD 1280
#define HH 128
#define DISROWS (NN*NN)

typedef short bf16x8 __attribute__((ext_vector_type(8)));
typedef short bf16x4 __attribute__((ext_vector_type(4)));
typedef float f32x4  __attribute__((ext_vector_type(4)));

__device__ __forceinline__ unsigned short f2bf(float x){
  unsigned u = __builtin_bit_cast(unsigned, x);
  u += 0x7fffu + ((u >> 16) & 1u);
  return (unsigned short)(u >> 16);
}
__device__ __forceinline__ float bf2f(unsigned short h){
  unsigned u = ((unsigned)h) << 16;
  return __builtin_bit_cast(float, u);
}
__device__ __forceinline__ short f2bf_fast(float x){
  return (short)__bfloat16_as_ushort(__float2bfloat16(x));
}
__device__ __forceinline__ void glds16(const short* g, short* l){
  __builtin_amdgcn_global_load_lds((const __attribute__((address_space(1))) void*)g,
                                   (__attribute__((address_space(3))) void*)l, 16, 0, 0);
}

// transpose W[R][C] -> Thi/Tlo[C][R] as bf16 hi (+ optional lo residual). 256 threads.
__device__ __forceinline__ void tsplit_body(const float* __restrict__ W,
                                            short* __restrict__ Thi, short* __restrict__ Tlo,
                                            int R, int C, int bx, int by, int t,
                                            float* tile /* [64][65] shared */){
  int rb = by*64, cb = bx*64;
  int r  = t >> 2;
  int cs = (t & 3) * 16;
  const float* sp = W + (long)(rb + r)*C + cb + cs;
  #pragma unroll
  for (int i = 0; i < 16; i += 4){
    f32x4 v = *(const f32x4*)(sp + i);
    tile[r*65 + cs+i+0] = v[0]; tile[r*65 + cs+i+1] = v[1];
    tile[r*65 + cs+i+2] = v[2]; tile[r*65 + cs+i+3] = v[3];
  }
  __syncthreads();
  int cp = t >> 2;
  int rs = (t & 3) * 16;
  bf16x8 vh0, vh1, vl0, vl1;
  #pragma unroll
  for (int i = 0; i < 8; ++i){
    float f = tile[(rs+i)*65 + cp];
    unsigned short h = f2bf(f);
    vh0[i] = (short)h; vl0[i] = (short)f2bf(f - bf2f(h));
  }
  #pragma unroll
  for (int i = 0; i < 8; ++i){
    float f = tile[(rs+8+i)*65 + cp];
    unsigned short h = f2bf(f);
    vh1[i] = (short)h; vl1[i] = (short)f2bf(f - bf2f(h));
  }
  long ob = (long)(cb + cp)*R + rb + rs;
  *(bf16x8*)&Thi[ob]   = vh0;
  *(bf16x8*)&Thi[ob+8] = vh1;
  if (Tlo){
    *(bf16x8*)&Tlo[ob]   = vl0;
    *(bf16x8*)&Tlo[ob+8] = vl1;
  }
}

// ---------------- mega-prep (512 thr): feat | graph CSR | Wd prep | tsplit(Wg0) ----------------
// blocks: [0,960) feat; [960] graph; [961,1002) dw; [1002,1402) tsplit Wg0
__global__ void k_prep(const float* __restrict__ lm, const float* __restrict__ nf,
                       float* __restrict__ x0,
                       const int* __restrict__ dst, const float* __restrict__ ef,
                       int* __restrict__ offs, int* __restrict__ sorted,
                       float* __restrict__ ew,
                       const float* __restrict__ Wd1, short* __restrict__ W1t,
                       const float* __restrict__ Wd2, short* __restrict__ W2t,
                       const float* __restrict__ Wg0, short* __restrict__ WtAh,
                       short* __restrict__ WtAl){
  __shared__ __align__(16) float sh[64*65];
  const int b = blockIdx.x;
  const int t = threadIdx.x;  // 512
  if (b < 960){
    int i = b*512 + t;
    int n = i / 1280;
    int d = i - n*1280;
    x0[i] = (d < 1024) ? lm[(n+1)*1024 + d] : nf[n*256 + (d-1024)];
    return;
  }
  if (b == 960){
    int* cnt = (int*)sh;
    int* base = cnt + 512;
    if (t < 512) cnt[t] = 0;
    __syncthreads();
    for (int e = t; e < EE; e += 512){
      atomicAdd(&cnt[dst[e]], 1);
      float f = ef[e];
      ew[e] = 1.0f/(f*f + 1e-6f);
    }
    __syncthreads();
    for (int off = 1; off < 512; off <<= 1){
      int v = (t >= off) ? cnt[t - off] : 0;
      __syncthreads();
      cnt[t] += v;
      __syncthreads();
    }
    if (t < NN){
      int excl = t ? cnt[t-1] : 0;
      offs[t] = excl;
      base[t] = excl;
    }
    if (t == 0) offs[NN] = EE;
    __syncthreads();
    for (int e = t; e < EE; e += 512){
      int p = atomicAdd(&base[dst[e]], 1);
      sorted[p] = e;
    }
    return;
  }
  if (b < 1002){
    int g = b - 961;
    if (g < 40){
      if (t < 256) tsplit_body(Wd1, W1t, nullptr, DD, HH, g & 1, g >> 1, t, sh);
      else { __syncthreads(); }
      return;
    }
    for (int i = t; i < 32*HH; i += 512){
      int c = i >> 7, h = i & 127;
      float v = (c < 30) ? Wd2[h*30 + c] : 0.f;
      W2t[i] = (short)f2bf(v);
    }
    return;
  }
  {
    int g = b - 1002;
    if (t < 256) tsplit_body(Wg0, WtAh, WtAl, DD, DD, g % 20, g / 20, t, sh);
    else { __syncthreads(); }
  }
}

// ---------------- edge aggregation: writes split bf16 Yh/Yl directly ----------------
__global__ void k_agg(const float* __restrict__ X, const float* __restrict__ ew,
                      const int* __restrict__ src, const int* __restrict__ offs,
                      const int* __restrict__ sorted,
                      short* __restrict__ Yh, short* __restrict__ Yl){
  __shared__ int   s_off[160];
  __shared__ float s_w[160];
  const int v = blockIdx.x;
  const int d = blockIdx.y*256 + threadIdx.x;
  const int t = threadIdx.x;
  float acc = X[(long)v*DD + d];
  const int b = offs[v], e = offs[v+1];
  for (int c0 = b; c0 < e; c0 += 160){
    int n = e - c0; if (n > 160) n = 160;
    __syncthreads();
    if (t < n){
      int eid = sorted[c0 + t];
      s_off[t] = src[eid]*DD;
      s_w[t]   = ew[eid];
    }
    __syncthreads();
    int k = 0;
    for (; k + 4 <= n; k += 4){
      acc += s_w[k]  *X[s_off[k]   + d];
      acc += s_w[k+1]*X[s_off[k+1] + d];
      acc += s_w[k+2]*X[s_off[k+2] + d];
      acc += s_w[k+3]*X[s_off[k+3] + d];
    }
    for (; k < n; ++k) acc += s_w[k]*X[s_off[k] + d];
  }
  unsigned short h = f2bf(acc);
  Yh[(long)v*DD + d] = (short)h;
  Yl[(long)v*DD + d] = (short)f2bf(acc - bf2f(h));
}

// ---------------- GIN GEMM, split-K=8, A pre-split (pure-copy staging) ----------------
__launch_bounds__(256, 2)
__global__ void k_gin_gemm(const short* __restrict__ Yh, const short* __restrict__ Yl,
                           const short* __restrict__ Whi, const short* __restrict__ Wlo,
                           float* __restrict__ P){
  __shared__ __align__(16) short Ahi[128*40], Alo[128*40], Bhi[128*40], Blo[128*40];
  const int m0 = blockIdx.x*128;
  const int n0 = blockIdx.y*128;
  const int kbase = blockIdx.z*160;
  const int t = threadIdx.x, w = t >> 6, lane = t & 63;
  const int l15 = lane & 15, l4 = lane >> 4;
  f32x4 acc[2][8];
  #pragma unroll
  for (int m = 0; m < 2; ++m)
    #pragma unroll
    for (int n = 0; n < 8; ++n) acc[m][n] = (f32x4){0.f,0.f,0.f,0.f};

  const int row = t >> 1, half = t & 1;
  const short* aph = Yh  + (long)(m0+row)*DD + half*16;
  const short* apl = Yl  + (long)(m0+row)*DD + half*16;
  const short* bph = Whi + (long)(n0+row)*DD + half*16;
  const short* bpl = Wlo + (long)(n0+row)*DD + half*16;

  for (int kk = 0; kk < 5; ++kk){
    int d0 = kbase + kk*32;
    __syncthreads();
    *(bf16x8*)&Ahi[row*40 + half*16]     = *(const bf16x8*)(aph + d0);
    *(bf16x8*)&Ahi[row*40 + half*16 + 8] = *(const bf16x8*)(aph + d0 + 8);
    *(bf16x8*)&Alo[row*40 + half*16]     = *(const bf16x8*)(apl + d0);
    *(bf16x8*)&Alo[row*40 + half*16 + 8] = *(const bf16x8*)(apl + d0 + 8);
    *(bf16x8*)&Bhi[row*40 + half*16]     = *(const bf16x8*)(bph + d0);
    *(bf16x8*)&Bhi[row*40 + half*16 + 8] = *(const bf16x8*)(bph + d0 + 8);
    *(bf16x8*)&Blo[row*40 + half*16]     = *(const bf16x8*)(bpl + d0);
    *(bf16x8*)&Blo[row*40 + half*16 + 8] = *(const bf16x8*)(bpl + d0 + 8);
    __syncthreads();

    bf16x8 ah[2], al[2];
    #pragma unroll
    for (int m = 0; m < 2; ++m){
      int rr = w*32 + m*16 + l15;
      ah[m] = *(const bf16x8*)&Ahi[rr*40 + l4*8];
      al[m] = *(const bf16x8*)&Alo[rr*40 + l4*8];
    }
    #pragma unroll
    for (int n = 0; n < 8; ++n){
      int rr = n*16 + l15;
      bf16x8 bh = *(const bf16x8*)&Bhi[rr*40 + l4*8];
      bf16x8 bl = *(const bf16x8*)&Blo[rr*40 + l4*8];
      #pragma unroll
      for (int m = 0; m < 2; ++m){
        acc[m][n] = __builtin_amdgcn_mfma_f32_16x16x32_bf16(ah[m], bh, acc[m][n], 0,0,0);
        acc[m][n] = __builtin_amdgcn_mfma_f32_16x16x32_bf16(ah[m], bl, acc[m][n], 0,0,0);
        acc[m][n] = __builtin_amdgcn_mfma_f32_16x16x32_bf16(al[m], bh, acc[m][n], 0,0,0);
      }
    }
  }
  float* Pz = P + (long)blockIdx.z*NN*DD;
  #pragma unroll
  for (int m = 0; m < 2; ++m){
    #pragma unroll
    for (int n = 0; n < 8; ++n){
      int gr0 = m0 + w*32 + m*16 + l4*4;
      int gc  = n0 + n*16 + l15;
      #pragma unroll
      for (int r = 0; r < 4; ++r)
        Pz[(long)(gr0+r)*DD + gc] = acc[m][n][r];
    }
  }
}

// red: blocks [0,480) sum 8 P slices + bias (+resid) -> Out; blocks [480,880): tsplit(Wg1)
__global__ void k_red_t(const float* __restrict__ P, const float* __restrict__ bias,
                        const float* __restrict__ resid, float* __restrict__ Out,
                        const float* __restrict__ Wg1, short* __restrict__ WtAh,
                        short* __restrict__ WtAl){
  __shared__ __align__(16) float sh[64*65];
  const int b = blockIdx.x;
  if (b >= 480){
    if (Wg1){
      int g = b - 480;
      tsplit_body(Wg1, WtAh, WtAl, DD, DD, g % 20, g / 20, threadIdx.x, sh);
    }
    return;
  }
  const int i = b*256 + threadIdx.x;
  const int col = (i*4) % DD;
  const f32x4* P4 = (const f32x4*)P;
  f32x4 s = P4[i];
  #pragma unroll
  for (int z = 1; z < 8; ++z) s += P4[i + z*122880];
  s += *(const f32x4*)(bias + col);
  if (resid) s += ((const f32x4*)resid)[i];
  ((f32x4*)Out)[i] = s;
}

// ---------------- fused dis MLP (R6 structure + packed-vector Sq builds) + mask head ----------------
// blocks [0,600): tile (ib: 8 i-rows, jb: 16 j-cols), jb_min = ib>>1. 256 thr / 4 waves.
// Wave w owns i-rows {2w, 2w+1}, all 8 h-tiles. 20 macros of K=64; W [2][128][64] via
// swizzled glds16; X [2][24][68] f32 in LDS; Sq builds as f32x4 vector ops (v_pk_*).
// Epilogue: TL b64-packed; layer-2; OT coalesced + mirror. blocks [600,664): mask head.
__launch_bounds__(256, 3)
__global__ void k_dis(const float* __restrict__ X, const short* __restrict__ W1t,
                      const float* __restrict__ bd1, const short* __restrict__ W2t,
                      const float* __restrict__ bd2, float* __restrict__ out,
                      const int* __restrict__ midx,
                      const float* __restrict__ Wm1, const float* __restrict__ bm1,
                      const float* __restrict__ Wm2, const float* __restrict__ bm2){
  __shared__ __align__(16) short smem[25088];   // 50176 B
  const int b = blockIdx.x;
  const int t = threadIdx.x;

  if (b >= 600){
    // ---- mask head ----
    float* tl = (float*)smem;
    int m = b - 600;
    if (t < HH){
      const float* x = X + (long)midx[m]*DD;
      float a0 = 0.f, a1 = 0.f, a2 = 0.f, a3 = 0.f;
      for (int d = 0; d < DD; d += 4){
        a0 += x[d]   * Wm1[(d)*HH + t];
        a1 += x[d+1] * Wm1[(d+1)*HH + t];
        a2 += x[d+2] * Wm1[(d+2)*HH + t];
        a3 += x[d+3] * Wm1[(d+3)*HH + t];
      }
      float v = a0 + a1 + a2 + a3 + bm1[t];
      tl[t] = v > 0.f ? v : 0.f;
    }
    __syncthreads();
    if (t < 2){
      float s = bm2[t];
      for (int h = 0; h < HH; ++h) s += tl[h]*Wm2[h*2 + t];
      out[(long)DISROWS*30 + m*2 + t] = tanhf(s);
    }
    return;
  }

  // triangular unrank: ib pairs (2k,2k+1) each have 24-k tiles
  int k = 0, rem = b;
  while (rem >= 2*(24 - k)){ rem -= 2*(24 - k); ++k; }
  int ib = 2*k;
  if (rem >= 24 - k){ ++ib; rem -= 24 - k; }
  const int jb = k + rem;
  const int i0 = ib*8, j0 = jb*16;

  const int w = t >> 6, lane = t & 63;
  const int l15 = lane & 15, l4 = lane >> 4;

  short* WA = smem;                       // [2][128][64] shorts (32768 B)
  float* XF = (float*)(smem + 16384);     // [2][24][68] f32 (13056 B)
  short* TL = smem;                       // alias: [128][136] shorts (34816 B)
  float* OT = (float*)(smem + 17408);     // alias: [128][30] f32 (15360 B)

  f32x4 acc[2][8];
  #pragma unroll
  for (int m = 0; m < 2; ++m)
    #pragma unroll
    for (int n = 0; n < 8; ++n) acc[m][n] = (f32x4){0.f,0.f,0.f,0.f};

  // W staging: wave w, inst i covers h rows [w*32+i*8, +8); lane -> h += lane>>3, slot lane&7
  const short* wsrc[4];
  #pragma unroll
  for (int i = 0; i < 4; ++i){
    int hb = w*32 + i*8 + (lane >> 3);
    wsrc[i] = W1t + (long)hb*DD + (((lane & 7) ^ (hb & 7))*8);
  }
  // X staging: 1536 f32/macro; thread t, g: idx=g*256+t; row=idx>>6 (0..23), col=idx&63
  const float* xsrc[6];
  int xli[6];
  #pragma unroll
  for (int g = 0; g < 6; ++g){
    int idx = g*256 + t;
    int rowl = idx >> 6, col = idx & 63;
    int grow = (rowl < 8) ? (i0 + rowl) : (j0 + rowl - 8);
    xsrc[g] = X + (long)grow*DD + col;
    xli[g] = rowl*68 + col;
  }

  // prologue: macro 0
  float xr[6];
  #pragma unroll
  for (int i = 0; i < 4; ++i)
    glds16(wsrc[i], WA + (w*32 + i*8)*64);
  #pragma unroll
  for (int g = 0; g < 6; ++g) xr[g] = xsrc[g][0];
  #pragma unroll
  for (int g = 0; g < 6; ++g) XF[xli[g]] = xr[g];
  __syncthreads();

  for (int mk = 0; mk < 20; ++mk){
    const int cb = mk & 1;
    short* WAc = WA + cb*8192;
    float* XFc = XF + cb*1632;
    short* WAn = WA + (cb^1)*8192;
    float* XFn = XF + (cb^1)*1632;
    if (mk < 19){
      #pragma unroll
      for (int i = 0; i < 4; ++i)
        glds16(wsrc[i] + (mk+1)*64, WAn + (w*32 + i*8)*64);
      #pragma unroll
      for (int g = 0; g < 6; ++g) xr[g] = xsrc[g][(mk+1)*64];
    }
    #pragma unroll
    for (int ks = 0; ks < 2; ++ks){
      f32x4 xj0 = *(const f32x4*)&XFc[(8 + l15)*68 + ks*32 + l4*8];
      f32x4 xj1 = *(const f32x4*)&XFc[(8 + l15)*68 + ks*32 + l4*8 + 4];
      bf16x8 a[2];
      #pragma unroll
      for (int m = 0; m < 2; ++m){
        const float* xip = &XFc[(2*w + m)*68 + ks*32 + l4*8];
        f32x4 xi0 = *(const f32x4*)xip;
        f32x4 xi1 = *(const f32x4*)(xip + 4);
        // vector sub/mul -> packed v_pk_add_f32 / v_pk_mul_f32
        f32x4 d0 = xj0 - xi0; d0 = d0*d0;
        f32x4 d1 = xj1 - xi1; d1 = d1*d1;
        bf16x8 av;
        #pragma unroll
        for (int q = 0; q < 4; ++q){
          av[q]   = f2bf_fast(d0[q]);
          av[4+q] = f2bf_fast(d1[q]);
        }
        a[m] = av;
      }
      #pragma unroll
      for (int n = 0; n < 8; ++n){
        bf16x8 wf = *(const bf16x8*)&WAc[(n*16 + l15)*64 + (((ks*4 + l4) ^ (l15 & 7))*8)];
        acc[0][n] = __builtin_amdgcn_mfma_f32_16x16x32_bf16(wf, a[0], acc[0][n], 0,0,0);
        acc[1][n] = __builtin_amdgcn_mfma_f32_16x16x32_bf16(wf, a[1], acc[1][n], 0,0,0);
      }
    }
    if (mk < 19){
      #pragma unroll
      for (int g = 0; g < 6; ++g) XFn[xli[g]] = xr[g];
    }
    __syncthreads();
  }

  // ---- TL[pair][h] write (b64 packed, 4 consecutive h) ----
  f32x4 bd1v[8];
  #pragma unroll
  for (int n = 0; n < 8; ++n) bd1v[n] = *(const f32x4*)(bd1 + n*16 + l4*4);
  #pragma unroll
  for (int m = 0; m < 2; ++m){
    int pair = (2*w + m)*16 + l15;
    #pragma unroll
    for (int n = 0; n < 8; ++n){
      bf16x4 pv;
      #pragma unroll
      for (int r = 0; r < 4; ++r){
        float v = acc[m][n][r] + bd1v[n][r];
        v = v > 0.f ? v : 0.f;
        pv[r] = f2bf_fast(v);
      }
      *(bf16x4*)&TL[pair*136 + n*16 + l4*4] = pv;
    }
  }
  __syncthreads();

  // ---- layer 2: wave w owns pairs [w*32, +32) ----
  f32x4 acc2[2][2];
  #pragma unroll
  for (int m2 = 0; m2 < 2; ++m2)
    #pragma unroll
    for (int nn = 0; nn < 2; ++nn) acc2[m2][nn] = (f32x4){0.f,0.f,0.f,0.f};
  #pragma unroll
  for (int hs = 0; hs < 4; ++hs){
    bf16x8 b2[2];
    #pragma unroll
    for (int nn = 0; nn < 2; ++nn)
      b2[nn] = *(const bf16x8*)&W2t[(nn*16 + l15)*HH + hs*32 + l4*8];
    #pragma unroll
    for (int m2 = 0; m2 < 2; ++m2){
      bf16x8 a2 = *(const bf16x8*)&TL[(w*32 + m2*16 + l15)*136 + hs*32 + l4*8];
      #pragma unroll
      for (int nn = 0; nn < 2; ++nn)
        acc2[m2][nn] = __builtin_amdgcn_mfma_f32_16x16x32_bf16(a2, b2[nn], acc2[m2][nn], 0,0,0);
    }
  }
  // OT[pair][30] f32
  #pragma unroll
  for (int m2 = 0; m2 < 2; ++m2){
    #pragma unroll
    for (int nn = 0; nn < 2; ++nn){
      int cc = nn*16 + l15;
      if (cc < 30){
        float b2v = bd2[cc];
        #pragma unroll
        for (int r = 0; r < 4; ++r)
          OT[(w*32 + m2*16 + l4*4 + r)*30 + cc] = acc2[m2][nn][r] + b2v;
      }
    }
  }
  __syncthreads();

  // ---- coalesced global writes from OT ----
  {
    // normal tile: 8 rows (gi), each 480 f32 contiguous
    int i = t >> 5;
    int ca = (t & 31)*15;
    long nbase = ((long)(i0 + i)*NN + j0)*30 + ca;
    const float* nsrc = OT + i*480 + ca;
    #pragma unroll
    for (int q = 0; q < 15; ++q) out[nbase + q] = nsrc[q];
    // mirror tile: 16 rows (gj), each 240 f32 contiguous
    int j = t >> 4;
    int s = t & 15;
    int ii = s >> 1;
    int c0 = (s & 1)*15;
    long mbase = ((long)(j0 + j)*NN + i0 + ii)*30 + c0;
    const float* msrc = OT + ii*480 + j*30 + c0;
    #pragma unroll
    for (int q = 0; q < 15; ++q) out[mbase + q] = msrc[q];
  }
}

// ---------------- launch ----------------
extern "C" void kernel_launch(void* const* d_in, const int* in_sizes, int n_in,
                              void* d_out, int out_size, void* d_ws, size_t ws_size,
                              hipStream_t stream){
  const float* lm   = (const float*)d_in[0];
  const float* nf   = (const float*)d_in[1];
  const float* ef   = (const float*)d_in[2];
  const int*   src  = (const int*)d_in[3];
  const int*   dst  = (const int*)d_in[4];
  const int*   midx = (const int*)d_in[5];
  const float* Wg0  = (const float*)d_in[6];
  const float* bg0  = (const float*)d_in[7];
  const float* Wg1  = (const float*)d_in[8];
  const float* bg1  = (const float*)d_in[9];
  const float* Wd1  = (const float*)d_in[10];
  const float* bd1  = (const float*)d_in[11];
  const float* Wd2  = (const float*)d_in[12];
  const float* bd2  = (const float*)d_in[13];
  const float* Wm1  = (const float*)d_in[14];
  const float* bm1  = (const float*)d_in[15];
  const float* Wm2  = (const float*)d_in[16];
  const float* bm2  = (const float*)d_in[17];
  float* dis = (float*)d_out;

  char* ws = (char*)d_ws;
  size_t off = 0;
  auto alloc = [&](size_t bytes)->void*{
    void* p = ws + off; off += (bytes + 255) & ~(size_t)255; return p;
  };
  float* x0   = (float*)alloc((size_t)NN*DD*4);
  float* hb   = (float*)alloc((size_t)NN*DD*4);
  short* Yh   = (short*)alloc((size_t)NN*DD*2);
  short* Yl   = (short*)alloc((size_t)NN*DD*2);
  float* ew   = (float*)alloc((size_t)EE*4);
  int*   offs = (int*)alloc((NN+1)*4);
  int*   sorted = (int*)alloc(EE*4);
  short* WtAh = (short*)alloc((size_t)DD*DD*2);
  short* WtAl = (short*)alloc((size_t)DD*DD*2);
  short* W1t  = (short*)alloc((size_t)HH*DD*2);
  short* W2t  = (short*)alloc((size_t)32*HH*2);
  float* P    = (float*)alloc((size_t)8*NN*DD*4);

  k_prep<<<1402,512,0,stream>>>(lm, nf, x0, dst, ef, offs, sorted, ew,
                                Wd1, W1t, Wd2, W2t, Wg0, WtAh, WtAl);

  k_agg<<<dim3(384,5),256,0,stream>>>(x0, ew, src, offs, sorted, Yh, Yl);
  k_gin_gemm<<<dim3(3,10,8),256,0,stream>>>(Yh, Yl, WtAh, WtAl, P);
  k_red_t<<<880,256,0,stream>>>(P, bg0, nullptr, hb, Wg1, WtAh, WtAl);

  k_agg<<<dim3(384,5),256,0,stream>>>(hb, ew, src, offs, sorted, Yh, Yl);
  k_gin_gemm<<<dim3(3,10,8),256,0,stream>>>(Yh, Yl, WtAh, WtAl, P);
  k_red_t<<<480,256,0,stream>>>(P, bg1, x0, hb, nullptr, nullptr, nullptr);

  k_dis<<<664,256,0,stream>>>(hb, W1t, bd1, W2t, bd2, dis,
                              midx, Wm1, bm1, Wm2, bm2);
}